// Round 11
// baseline (321.590 us; speedup 1.0000x reference)
//
#include <hip/hip_runtime.h>
#include <hip/hip_bf16.h>
#include <cstdio>

typedef unsigned short u16;
typedef __attribute__((ext_vector_type(4))) float f32x4;
typedef __attribute__((ext_vector_type(8))) short s16x8;

#define LOG2E 1.4426950408889634f

__device__ __forceinline__ u16 bf16b(float f) {
  union { float f; unsigned u; } c; c.f = f;
  unsigned u = c.u;
  return (u16)((u + 0x7FFFu + ((u >> 16) & 1u)) >> 16);
}

__device__ __forceinline__ void load16(const void* g, void* l) {
  __builtin_amdgcn_global_load_lds(
      (const __attribute__((address_space(1))) void*)g,
      (__attribute__((address_space(3))) void*)l, 16, 0, 0);
}

// ---------------- converters (x and W fused into one launch) ----------------

__global__ __launch_bounds__(256) void cvt_all_k(const float* __restrict__ x,
                                                 const float* __restrict__ Wq,
                                                 const float* __restrict__ Wk,
                                                 const float* __restrict__ Wv,
                                                 u16* __restrict__ xb,
                                                 u16* __restrict__ Wcat) {
  int bid = blockIdx.x;
  if (bid < 16384) {
    long i = ((long)bid * 256 + threadIdx.x) * 4;
    float4 f = *(const float4*)&x[i];
    unsigned lo = (unsigned)bf16b(f.x) | ((unsigned)bf16b(f.y) << 16);
    unsigned hi = (unsigned)bf16b(f.z) | ((unsigned)bf16b(f.w) << 16);
    uint2 v; v.x = lo; v.y = hi;
    *(uint2*)&xb[i] = v;
  } else {
    int idx = (bid - 16384) * 256 + threadIdx.x;  // 640*512
    int nn = idx >> 9, k = idx & 511;
    float v;
    if (nn < 64)       v = Wq[k * 64 + nn];
    else if (nn < 128) v = Wk[k * 64 + (nn - 64)];
    else               v = Wv[k * 512 + (nn - 128)];
    Wcat[idx] = bf16b(v);
  }
}

// ---------------- projection GEMM: C[m,n] = sum_k A[m,k]*B[n,k] ----------------
// writes Qb/Kb bf16 row-major and Vt TRANSPOSED ([b][c][n]) directly.
__global__ __launch_bounds__(256, 2) void projGemm(
    const u16* __restrict__ A, const u16* __restrict__ B,
    u16* __restrict__ Qb, u16* __restrict__ Kb, u16* __restrict__ Vt,
    const float* __restrict__ bq, const float* __restrict__ bk,
    const float* __restrict__ bv) {
  constexpr int BM = 128, BN = 128, FM = 4, FN = 4;
  __shared__ __align__(16) u16 At[BM * 64];
  __shared__ __align__(16) u16 Bt[BN * 64];
  const int tid = threadIdx.x;
  const int lane = tid & 63, w = tid >> 6;
  const int wr = w >> 1, wc = w & 1;
  const int l15 = lane & 15, lhi = lane >> 4;
  const long m0 = (long)blockIdx.x * BM;
  const long n0 = (long)blockIdx.y * BN;

  f32x4 acc[FM][FN] = {};

  for (int k0 = 0; k0 < 512; k0 += 64) {
#pragma unroll
    for (int it = 0; it < 8; ++it) {
      int q = it * 256 + tid;
      if (q < BM * 8) {
        int row = q >> 3, c8 = q & 7;
        load16(A + (m0 + row) * 512 + k0 + c8 * 8, &At[q * 8]);
      } else {
        int q2 = q - BM * 8;
        int row = q2 >> 3, c8 = q2 & 7;
        load16(B + (n0 + row) * 512 + k0 + c8 * 8, &Bt[q2 * 8]);
      }
    }
    __syncthreads();
#pragma unroll
    for (int kk = 0; kk < 64; kk += 32) {
      s16x8 af[FM], bf[FN];
#pragma unroll
      for (int i = 0; i < FM; ++i)
        af[i] = *(const s16x8*)&At[(wr * 64 + i * 16 + l15) * 64 + kk + lhi * 8];
#pragma unroll
      for (int j = 0; j < FN; ++j)
        bf[j] = *(const s16x8*)&Bt[(wc * 64 + j * 16 + l15) * 64 + kk + lhi * 8];
#pragma unroll
      for (int i = 0; i < FM; ++i)
#pragma unroll
        for (int j = 0; j < FN; ++j)
          acc[i][j] = __builtin_amdgcn_mfma_f32_16x16x32_bf16(af[i], bf[j],
                                                              acc[i][j], 0, 0, 0);
    }
    __syncthreads();
  }

#pragma unroll
  for (int i = 0; i < FM; ++i) {
#pragma unroll
    for (int j = 0; j < FN; ++j) {
      long mm = m0 + wr * 64 + i * 16 + lhi * 4;
      long nn = n0 + wc * 64 + j * 16 + l15;
      if (nn < 64) {
        float bb = bq[nn];
#pragma unroll
        for (int r = 0; r < 4; ++r)
          Qb[(mm + r) * 64 + nn] = bf16b(acc[i][j][r] + bb);
      } else if (nn < 128) {
        float bb = bk[nn - 64];
#pragma unroll
        for (int r = 0; r < 4; ++r)
          Kb[(mm + r) * 64 + nn - 64] = bf16b(acc[i][j][r] + bb);
      } else {
        long c = nn - 128;
        float bb = bv[c];
        unsigned u01 = (unsigned)bf16b(acc[i][j][0] + bb) |
                       ((unsigned)bf16b(acc[i][j][1] + bb) << 16);
        unsigned u23 = (unsigned)bf16b(acc[i][j][2] + bb) |
                       ((unsigned)bf16b(acc[i][j][3] + bb) << 16);
        uint2 u; u.x = u01; u.y = u23;
        *(uint2*)&Vt[(mm >> 12) * 512 * 4096 + c * 4096 + (mm & 4095)] = u;
      }
    }
  }
}

// ---------------- softmax row stats (over j) via S recompute ----------------
__global__ __launch_bounds__(256, 2) void stats_k(const u16* __restrict__ Qb,
                                                  const u16* __restrict__ Kb,
                                                  float* __restrict__ m_part,
                                                  float* __restrict__ l_part) {
  const int b = blockIdx.z, jc = blockIdx.y;
  const long i0 = (long)blockIdx.x * 128;
  const u16* Q = Qb + (long)b * 4096 * 64;
  const u16* Kp = Kb + (long)b * 4096 * 64;
  __shared__ __align__(16) u16 Qt[128 * 64];
  __shared__ __align__(16) u16 Kt[128 * 64];
  const int tid = threadIdx.x, lane = tid & 63, w = tid >> 6;
  const int l15 = lane & 15, lhi = lane >> 4;

#pragma unroll
  for (int it = 0; it < 4; ++it) {
    int q = it * 256 + tid;
    int row = q >> 3, c8 = q & 7;
    load16(Q + (i0 + row) * 64 + c8 * 8, &Qt[q * 8]);
  }

  float mrun[2][4], lrun[2][4];
#pragma unroll
  for (int i = 0; i < 2; ++i)
#pragma unroll
    for (int r = 0; r < 4; ++r) { mrun[i][r] = -1e30f; lrun[i][r] = 0.f; }

  for (int jt = 0; jt < 8; ++jt) {
    long j0 = (long)jc * 1024 + jt * 128;
#pragma unroll
    for (int it = 0; it < 4; ++it) {
      int q = it * 256 + tid;
      int row = q >> 3, c8 = q & 7;
      load16(Kp + (j0 + row) * 64 + c8 * 8, &Kt[q * 8]);
    }
    __syncthreads();
    f32x4 acc[2][8] = {};
#pragma unroll
    for (int kk = 0; kk < 64; kk += 32) {
      s16x8 af[2], bf[8];
#pragma unroll
      for (int i = 0; i < 2; ++i)
        af[i] = *(const s16x8*)&Qt[(w * 32 + i * 16 + l15) * 64 + kk + lhi * 8];
#pragma unroll
      for (int j = 0; j < 8; ++j)
        bf[j] = *(const s16x8*)&Kt[(j * 16 + l15) * 64 + kk + lhi * 8];
#pragma unroll
      for (int i = 0; i < 2; ++i)
#pragma unroll
        for (int j = 0; j < 8; ++j)
          acc[i][j] = __builtin_amdgcn_mfma_f32_16x16x32_bf16(af[i], bf[j],
                                                              acc[i][j], 0, 0, 0);
    }
#pragma unroll
    for (int i = 0; i < 2; ++i)
#pragma unroll
      for (int r = 0; r < 4; ++r) {
        float tm = acc[i][0][r];
#pragma unroll
        for (int j = 1; j < 8; ++j) tm = fmaxf(tm, acc[i][j][r]);
        float mo = mrun[i][r];
        float mn = fmaxf(mo, tm);
        float s = 0.f;
#pragma unroll
        for (int j = 0; j < 8; ++j) s += __expf(acc[i][j][r] - mn);
        lrun[i][r] = lrun[i][r] * __expf(mo - mn) + s;
        mrun[i][r] = mn;
      }
    __syncthreads();
  }

#pragma unroll
  for (int i = 0; i < 2; ++i)
#pragma unroll
    for (int r = 0; r < 4; ++r) {
      float m = mrun[i][r], l = lrun[i][r];
#pragma unroll
      for (int d = 1; d < 16; d <<= 1) {
        float mo = __shfl_xor(m, d);
        float lo = __shfl_xor(l, d);
        float mn = fmaxf(m, mo);
        l = l * __expf(m - mn) + lo * __expf(mo - mn);
        m = mn;
      }
      if (l15 == 0) {
        long ig = i0 + w * 32 + i * 16 + lhi * 4 + r;
        long idx = ((long)(b * 4 + jc)) * 4096 + ig;
        m_part[idx] = m;
        l_part[idx] = l;
      }
    }
}

// merged stats: M2 = (m + ln l) * log2e, so P = exp2(s*log2e - M2)
__global__ __launch_bounds__(256) void merge_k(const float* __restrict__ m_part,
                                               const float* __restrict__ l_part,
                                               float* __restrict__ mfin) {
  int idx = blockIdx.x * 256 + threadIdx.x;  // 8*4096
  int b = idx >> 12, i = idx & 4095;
  float m = -1e30f, l = 0.f;
#pragma unroll
  for (int jc = 0; jc < 4; ++jc) {
    long o = ((long)(b * 4 + jc)) * 4096 + i;
    float mp = m_part[o], lp = l_part[o];
    float mn = fmaxf(m, mp);
    l = l * __expf(m - mn) + lp * __expf(mp - mn);
    m = mn;
  }
  mfin[idx] = fmaf(m, LOG2E, __log2f(l));
}

// ---------------- fused P·V v11 — r10 dataflow + m201-style phase pacing ----
// 8-wave block (512 thr): out[b, j0:+128, 0:512]. Grid 32x8 = 256 = 1/CU.
// Region(t): [bar vmcnt0/lgkm0] -> qf/mv(t+1) + V(t+1) DMA -> GEMM2(t) split
// into 4 phases {4 vb reads -> 16 MFMA (setprio) -> pacing s_barrier}, with
// the reg-only GEMM1(t+1) halves (fi=0/1) interleaved between phase pairs.
// Phase barriers exchange NO data (all Vc/Pl hazards guarded by top barrier).
__global__ __launch_bounds__(512, 2) void fusedPV(
    const u16* __restrict__ Qb, const u16* __restrict__ Kb,
    const u16* __restrict__ Vt, const float* __restrict__ mfin,
    const float* __restrict__ x, const float* __restrict__ gamma,
    float* __restrict__ out) {
  __shared__ __align__(16) u16 Vc[2][512 * 64];  // 128 KB
  __shared__ __align__(16) u16 Pl[2][128 * 64];  // 32 KB (Pl[0] = K staging)
  const int tid = threadIdx.x, lane = tid & 63, w = tid >> 6;  // w 0..7
  const int l15 = lane & 15, lhi = lane >> 4;
  const int wi = w & 1, wj = w >> 1;    // GEMM1: i-half(32) x j-quarter(32)
  const int wjj = w & 1, wcc = w >> 1;  // GEMM2: j-half(64) x c-quarter(128)
  // XCD remap: 256 blocks = 8 XCDs x 32; XCD k owns batch k (V 4MB = its L2)
  const int s = blockIdx.x + 32 * blockIdx.z;
  const int pi = (s & 7) * 32 + (s >> 3);
  const int b = pi >> 5;
  const long j0 = (long)(pi & 31) * 128;
  const u16* Qg = Qb + (long)b * 4096 * 64;
  const u16* Kg = Kb + (long)b * 4096 * 64;
  const u16* Vg = Vt + (long)b * 512 * 4096;
  const float* mg = mfin + (long)b * 4096;
  const float gma = gamma[0];

  // ---- prologue: stage K tile (128x128B) via Pl[0], hoist kf to regs ----
#pragma unroll
  for (int p = 0; p < 2; ++p) {
    int q = p * 512 + tid;
    int r = q >> 3, col = q & 7, cg = col ^ (r & 7);
    load16(Kg + (j0 + r) * 64 + cg * 8,
           (char*)&Pl[0][0] + r * 128 + col * 16);
  }
  asm volatile("s_waitcnt vmcnt(0) lgkmcnt(0)\n\ts_barrier" ::: "memory");
  s16x8 kf[2][2];  // loop-invariant K fragments (16 VGPR)
#pragma unroll
  for (int fj = 0; fj < 2; ++fj)
#pragma unroll
    for (int kx = 0; kx < 2; ++kx) {
      int r = wj * 32 + fj * 16 + l15;
      kf[fj][kx] = *(const s16x8*)((const char*)&Pl[0][0] + r * 128 +
                                   (((kx * 32 + lhi * 8) * 2) ^ ((r & 7) << 4)));
    }
  __syncthreads();  // kf reads done before Pl[0] reused for P

  f32x4 acc2[4][8] = {};
  s16x8 qf[2][2];
  f32x4 mv[2];

  // ---- t=0 preload: qf/mv first (so their use = vmcnt(8)), then V(0) DMA ----
#pragma unroll
  for (int fi = 0; fi < 2; ++fi) {
#pragma unroll
    for (int kx = 0; kx < 2; ++kx)
      qf[fi][kx] = *(const s16x8*)&Qg[(long)(wi * 32 + fi * 16 + l15) * 64 +
                                      kx * 32 + lhi * 8];
    mv[fi] = *(const f32x4*)&mg[wi * 32 + fi * 16 + lhi * 4];
  }
#pragma unroll
  for (int p = 0; p < 8; ++p) {
    int q = p * 512 + tid;
    int r = q >> 3, col = q & 7, cg = col ^ (r & 7);
    load16(Vg + (long)r * 4096 + cg * 8,
           (char*)&Vc[0][0] + r * 128 + col * 16);
  }
  // GEMM1(0) + epi -> Pl[0]
#pragma unroll
  for (int fi = 0; fi < 2; ++fi) {
    f32x4 a1[2] = {};
#pragma unroll
    for (int kx = 0; kx < 2; ++kx)
#pragma unroll
      for (int fj = 0; fj < 2; ++fj)
        a1[fj] = __builtin_amdgcn_mfma_f32_16x16x32_bf16(qf[fi][kx],
                                                         kf[fj][kx], a1[fj],
                                                         0, 0, 0);
    const int i0l = wi * 32 + fi * 16 + lhi * 4;
#pragma unroll
    for (int fj = 0; fj < 2; ++fj) {
      int j = wj * 32 + fj * 16 + l15;
      float p0 = __builtin_amdgcn_exp2f(fmaf(a1[fj][0], LOG2E, -mv[fi][0]));
      float p1 = __builtin_amdgcn_exp2f(fmaf(a1[fj][1], LOG2E, -mv[fi][1]));
      float p2 = __builtin_amdgcn_exp2f(fmaf(a1[fj][2], LOG2E, -mv[fi][2]));
      float p3 = __builtin_amdgcn_exp2f(fmaf(a1[fj][3], LOG2E, -mv[fi][3]));
      uint2 u;
      u.x = (unsigned)bf16b(p0) | ((unsigned)bf16b(p1) << 16);
      u.y = (unsigned)bf16b(p2) | ((unsigned)bf16b(p3) << 16);
      *(uint2*)((char*)&Pl[0][0] + j * 128 + ((i0l * 2) ^ ((j & 7) << 4))) = u;
    }
  }

  for (int t = 0; t < 64; ++t) {
    const char* plc = (const char*)&Pl[t & 1][0];
    char* pln = (char*)&Pl[(t + 1) & 1][0];
    const char* vcc = (const char*)&Vc[t & 1][0];
    // top barrier: publish Pl[t&1]; drain V(t) DMA; free Vc[~t], Pl[~t]
    asm volatile("s_waitcnt vmcnt(0) lgkmcnt(0)\n\ts_barrier" ::: "memory");
    if (t < 63) {
      const long i2 = (long)(t + 1) * 64;
      // qf/mv(t+1) first (their use -> counted vmcnt, keeps DMA in flight)
#pragma unroll
      for (int fi = 0; fi < 2; ++fi) {
#pragma unroll
        for (int kx = 0; kx < 2; ++kx)
          qf[fi][kx] = *(const s16x8*)&Qg[(i2 + wi * 32 + fi * 16 + l15) * 64 +
                                          kx * 32 + lhi * 8];
        mv[fi] = *(const f32x4*)&mg[i2 + wi * 32 + fi * 16 + lhi * 4];
      }
      // V(t+1) DMA -> Vc[~t] (freed by the barrier above)
#pragma unroll
      for (int p = 0; p < 8; ++p) {
        int q = p * 512 + tid;
        int r = q >> 3, col = q & 7, cg = col ^ (r & 7);
        load16(Vg + (long)r * 4096 + i2 + cg * 8,
               (char*)&Vc[(t + 1) & 1][0] + r * 128 + col * 16);
      }
    }
    __builtin_amdgcn_sched_barrier(0);  // pin load issue before compute

    // ---- GEMM2(t) in 4 paced phases; GEMM1(t+1) halves interleaved ----
    s16x8 pa[4], vb[4];
    // pa for kx=0
#pragma unroll
    for (int fm = 0; fm < 4; ++fm) {
      int r = wjj * 64 + fm * 16 + l15;
      pa[fm] = *(const s16x8*)(plc + r * 128 +
                               (((0 + lhi * 8) * 2) ^ ((r & 7) << 4)));
    }
    // phase 1: kx0, fn 0-3
#pragma unroll
    for (int fn = 0; fn < 4; ++fn) {
      int r = wcc * 128 + fn * 16 + l15;
      vb[fn] = *(const s16x8*)(vcc + r * 128 +
                               (((0 + lhi * 8) * 2) ^ ((r & 7) << 4)));
    }
    __builtin_amdgcn_s_setprio(1);
#pragma unroll
    for (int fn = 0; fn < 4; ++fn)
#pragma unroll
      for (int fm = 0; fm < 4; ++fm)
        acc2[fm][fn] = __builtin_amdgcn_mfma_f32_16x16x32_bf16(
            pa[fm], vb[fn], acc2[fm][fn], 0, 0, 0);
    __builtin_amdgcn_s_setprio(0);
    asm volatile("s_barrier" ::: "memory");  // pacing only
    // phase 2: kx0, fn 4-7
#pragma unroll
    for (int fn = 0; fn < 4; ++fn) {
      int r = wcc * 128 + (4 + fn) * 16 + l15;
      vb[fn] = *(const s16x8*)(vcc + r * 128 +
                               (((0 + lhi * 8) * 2) ^ ((r & 7) << 4)));
    }
    __builtin_amdgcn_s_setprio(1);
#pragma unroll
    for (int fn = 0; fn < 4; ++fn)
#pragma unroll
      for (int fm = 0; fm < 4; ++fm)
        acc2[fm][4 + fn] = __builtin_amdgcn_mfma_f32_16x16x32_bf16(
            pa[fm], vb[fn], acc2[fm][4 + fn], 0, 0, 0);
    __builtin_amdgcn_s_setprio(0);
    asm volatile("s_barrier" ::: "memory");  // pacing only
    // GEMM1(t+1) fi=0 (reg-only MFMA + VALU epi fills LDS bubbles)
    if (t < 63) {
      f32x4 a1[2] = {};
#pragma unroll
      for (int kx = 0; kx < 2; ++kx)
#pragma unroll
        for (int fj = 0; fj < 2; ++fj)
          a1[fj] = __builtin_amdgcn_mfma_f32_16x16x32_bf16(qf[0][kx],
                                                           kf[fj][kx], a1[fj],
                                                           0, 0, 0);
      const int i0l = wi * 32 + lhi * 4;
#pragma unroll
      for (int fj = 0; fj < 2; ++fj) {
        int j = wj * 32 + fj * 16 + l15;
        float p0 = __builtin_amdgcn_exp2f(fmaf(a1[fj][0], LOG2E, -mv[0][0]));
        float p1 = __builtin_amdgcn_exp2f(fmaf(a1[fj][1], LOG2E, -mv[0][1]));
        float p2 = __builtin_amdgcn_exp2f(fmaf(a1[fj][2], LOG2E, -mv[0][2]));
        float p3 = __builtin_amdgcn_exp2f(fmaf(a1[fj][3], LOG2E, -mv[0][3]));
        uint2 u;
        u.x = (unsigned)bf16b(p0) | ((unsigned)bf16b(p1) << 16);
        u.y = (unsigned)bf16b(p2) | ((unsigned)bf16b(p3) << 16);
        *(uint2*)(pln + j * 128 + ((i0l * 2) ^ ((j & 7) << 4))) = u;
      }
    }
    // pa for kx=1
#pragma unroll
    for (int fm = 0; fm < 4; ++fm) {
      int r = wjj * 64 + fm * 16 + l15;
      pa[fm] = *(const s16x8*)(plc + r * 128 +
                               (((32 + lhi * 8) * 2) ^ ((r & 7) << 4)));
    }
    // phase 3: kx1, fn 0-3
#pragma unroll
    for (int fn = 0; fn < 4; ++fn) {
      int r = wcc * 128 + fn * 16 + l15;
      vb[fn] = *(const s16x8*)(vcc + r * 128 +
                               (((32 + lhi * 8) * 2) ^ ((r & 7) << 4)));
    }
    __builtin_amdgcn_s_setprio(1);
#pragma unroll
    for (int fn = 0; fn < 4; ++fn)
#pragma unroll
      for (int fm = 0; fm < 4; ++fm)
        acc2[fm][fn] = __builtin_amdgcn_mfma_f32_16x16x32_bf16(
            pa[fm], vb[fn], acc2[fm][fn], 0, 0, 0);
    __builtin_amdgcn_s_setprio(0);
    asm volatile("s_barrier" ::: "memory");  // pacing only
    // phase 4: kx1, fn 4-7 (no trailing barrier; top barrier follows)
#pragma unroll
    for (int fn = 0; fn < 4; ++fn) {
      int r = wcc * 128 + (4 + fn) * 16 + l15;
      vb[fn] = *(const s16x8*)(vcc + r * 128 +
                               (((32 + lhi * 8) * 2) ^ ((r & 7) << 4)));
    }
    __builtin_amdgcn_s_setprio(1);
#pragma unroll
    for (int fn = 0; fn < 4; ++fn)
#pragma unroll
      for (int fm = 0; fm < 4; ++fm)
        acc2[fm][4 + fn] = __builtin_amdgcn_mfma_f32_16x16x32_bf16(
            pa[fm], vb[fn], acc2[fm][4 + fn], 0, 0, 0);
    __builtin_amdgcn_s_setprio(0);
    // GEMM1(t+1) fi=1
    if (t < 63) {
      f32x4 a1[2] = {};
#pragma unroll
      for (int kx = 0; kx < 2; ++kx)
#pragma unroll
        for (int fj = 0; fj < 2; ++fj)
          a1[fj] = __builtin_amdgcn_mfma_f32_16x16x32_bf16(qf[1][kx],
                                                           kf[fj][kx], a1[fj],
                                                           0, 0, 0);
      const int i0l = wi * 32 + 16 + lhi * 4;
#pragma unroll
      for (int fj = 0; fj < 2; ++fj) {
        int j = wj * 32 + fj * 16 + l15;
        float p0 = __builtin_amdgcn_exp2f(fmaf(a1[fj][0], LOG2E, -mv[1][0]));
        float p1 = __builtin_amdgcn_exp2f(fmaf(a1[fj][1], LOG2E, -mv[1][1]));
        float p2 = __builtin_amdgcn_exp2f(fmaf(a1[fj][2], LOG2E, -mv[1][2]));
        float p3 = __builtin_amdgcn_exp2f(fmaf(a1[fj][3], LOG2E, -mv[1][3]));
        uint2 u;
        u.x = (unsigned)bf16b(p0) | ((unsigned)bf16b(p1) << 16);
        u.y = (unsigned)bf16b(p2) | ((unsigned)bf16b(p3) << 16);
        *(uint2*)(pln + j * 128 + ((i0l * 2) ^ ((j & 7) << 4))) = u;
      }
    }
  }

  // final epilogue: out = gamma*acc2 + x
#pragma unroll
  for (int fm = 0; fm < 4; ++fm) {
#pragma unroll
    for (int fn = 0; fn < 8; ++fn) {
      long j = j0 + wjj * 64 + fm * 16 + lhi * 4;
      long c = wcc * 128 + fn * 16 + l15;
#pragma unroll
      for (int r = 0; r < 4; ++r) {
        long o = ((long)b * 4096 + j + r) * 512 + c;
        out[o] = gma * acc2[fm][fn][r] + x[o];
      }
    }
  }
}

// ---------------- host ----------------

extern "C" void kernel_launch(void* const* d_in, const int* in_sizes, int n_in,
                              void* d_out, int out_size, void* d_ws,
                              size_t ws_size, hipStream_t stream) {
  const float* x = (const float*)d_in[0];
  const float* Wq = (const float*)d_in[1];
  const float* bq = (const float*)d_in[2];
  const float* Wk = (const float*)d_in[3];
  const float* bk = (const float*)d_in[4];
  const float* Wv = (const float*)d_in[5];
  const float* bv = (const float*)d_in[6];
  const float* gamma = (const float*)d_in[7];
  float* out = (float*)d_out;

  char* ws = (char*)d_ws;
  size_t off = 0;
  auto alloc = [&](size_t bytes) {
    char* p = ws + off;
    off += (bytes + 255) & ~(size_t)255;
    return p;
  };
  u16* xb = (u16*)alloc((size_t)32768 * 512 * 2);        // 32 MB
  u16* Wcat = (u16*)alloc((size_t)640 * 512 * 2);        // 640 KB
  u16* Qb = (u16*)alloc((size_t)8 * 4096 * 64 * 2);      // 4 MB
  u16* Kb = (u16*)alloc((size_t)8 * 4096 * 64 * 2);      // 4 MB
  u16* Vt = (u16*)alloc((size_t)8 * 512 * 4096 * 2);     // 32 MB
  float* m_part = (float*)alloc((size_t)8 * 4 * 4096 * 4);
  float* l_part = (float*)alloc((size_t)8 * 4 * 4096 * 4);
  float* mfin = (float*)alloc((size_t)8 * 4096 * 4);
  if (off > ws_size) {
    fprintf(stderr, "kernel_launch: ws too small: need %zu have %zu\n", off,
            ws_size);
    return;
  }

  // 1) dtype conversions (x + W in one launch)
  cvt_all_k<<<16384 + 1280, 256, 0, stream>>>(x, Wq, Wk, Wv, xb, Wcat);
  // 2) fused q/k/v projection GEMM (M=32768, N=640, K=512); writes Vt directly
  projGemm<<<dim3(256, 5, 1), 256, 0, stream>>>(xb, Wcat, Qb, Kb, Vt, bq, bk,
                                                bv);
  // 3) softmax row stats (recompute S)
  stats_k<<<dim3(32, 4, 8), 256, 0, stream>>>(Qb, Kb, m_part, l_part);
  merge_k<<<128, 256, 0, stream>>>(m_part, l_part, mfin);
  // 4) fused P recompute + P·V + residual epilogue (all 8 batches, full c)
  fusedPV<<<dim3(32, 1, 8), 512, 0, stream>>>(Qb, Kb, Vt, mfin, x, gamma,
                                              out);
}

// Round 12
// 284.873 us; speedup vs baseline: 1.1289x; 1.1289x over previous
//
#include <hip/hip_runtime.h>
#include <hip/hip_bf16.h>
#include <cstdio>

typedef unsigned short u16;
typedef __attribute__((ext_vector_type(4))) float f32x4;
typedef __attribute__((ext_vector_type(8))) short s16x8;

#define LOG2E 1.4426950408889634f

__device__ __forceinline__ u16 bf16b(float f) {
  union { float f; unsigned u; } c; c.f = f;
  unsigned u = c.u;
  return (u16)((u + 0x7FFFu + ((u >> 16) & 1u)) >> 16);
}

__device__ __forceinline__ void load16(const void* g, void* l) {
  __builtin_amdgcn_global_load_lds(
      (const __attribute__((address_space(1))) void*)g,
      (__attribute__((address_space(3))) void*)l, 16, 0, 0);
}

// ---------------- converters (x and W fused into one launch) ----------------

__global__ __launch_bounds__(256) void cvt_all_k(const float* __restrict__ x,
                                                 const float* __restrict__ Wq,
                                                 const float* __restrict__ Wk,
                                                 const float* __restrict__ Wv,
                                                 u16* __restrict__ xb,
                                                 u16* __restrict__ Wcat) {
  int bid = blockIdx.x;
  if (bid < 16384) {
    long i = ((long)bid * 256 + threadIdx.x) * 4;
    float4 f = *(const float4*)&x[i];
    unsigned lo = (unsigned)bf16b(f.x) | ((unsigned)bf16b(f.y) << 16);
    unsigned hi = (unsigned)bf16b(f.z) | ((unsigned)bf16b(f.w) << 16);
    uint2 v; v.x = lo; v.y = hi;
    *(uint2*)&xb[i] = v;
  } else {
    int idx = (bid - 16384) * 256 + threadIdx.x;  // 640*512
    int nn = idx >> 9, k = idx & 511;
    float v;
    if (nn < 64)       v = Wq[k * 64 + nn];
    else if (nn < 128) v = Wk[k * 64 + (nn - 64)];
    else               v = Wv[k * 512 + (nn - 128)];
    Wcat[idx] = bf16b(v);
  }
}

// ---------------- projection GEMM: C[m,n] = sum_k A[m,k]*B[n,k] ----------------
// writes Qb/Kb bf16 row-major and Vt TRANSPOSED ([b][c][n]) directly.
// (A-tile XCD locality is natural: the 5 blocks sharing an A-tile differ only
// in blockIdx.y and 256%8==0 keeps x%8 invariant.)
__global__ __launch_bounds__(256, 2) void projGemm(
    const u16* __restrict__ A, const u16* __restrict__ B,
    u16* __restrict__ Qb, u16* __restrict__ Kb, u16* __restrict__ Vt,
    const float* __restrict__ bq, const float* __restrict__ bk,
    const float* __restrict__ bv) {
  constexpr int BM = 128, BN = 128, FM = 4, FN = 4;
  __shared__ __align__(16) u16 At[BM * 64];
  __shared__ __align__(16) u16 Bt[BN * 64];
  const int tid = threadIdx.x;
  const int lane = tid & 63, w = tid >> 6;
  const int wr = w >> 1, wc = w & 1;
  const int l15 = lane & 15, lhi = lane >> 4;
  const long m0 = (long)blockIdx.x * BM;
  const long n0 = (long)blockIdx.y * BN;

  f32x4 acc[FM][FN] = {};

  for (int k0 = 0; k0 < 512; k0 += 64) {
#pragma unroll
    for (int it = 0; it < 8; ++it) {
      int q = it * 256 + tid;
      if (q < BM * 8) {
        int row = q >> 3, c8 = q & 7;
        load16(A + (m0 + row) * 512 + k0 + c8 * 8, &At[q * 8]);
      } else {
        int q2 = q - BM * 8;
        int row = q2 >> 3, c8 = q2 & 7;
        load16(B + (n0 + row) * 512 + k0 + c8 * 8, &Bt[q2 * 8]);
      }
    }
    __syncthreads();
#pragma unroll
    for (int kk = 0; kk < 64; kk += 32) {
      s16x8 af[FM], bf[FN];
#pragma unroll
      for (int i = 0; i < FM; ++i)
        af[i] = *(const s16x8*)&At[(wr * 64 + i * 16 + l15) * 64 + kk + lhi * 8];
#pragma unroll
      for (int j = 0; j < FN; ++j)
        bf[j] = *(const s16x8*)&Bt[(wc * 64 + j * 16 + l15) * 64 + kk + lhi * 8];
#pragma unroll
      for (int i = 0; i < FM; ++i)
#pragma unroll
        for (int j = 0; j < FN; ++j)
          acc[i][j] = __builtin_amdgcn_mfma_f32_16x16x32_bf16(af[i], bf[j],
                                                              acc[i][j], 0, 0, 0);
    }
    __syncthreads();
  }

#pragma unroll
  for (int i = 0; i < FM; ++i) {
#pragma unroll
    for (int j = 0; j < FN; ++j) {
      long mm = m0 + wr * 64 + i * 16 + lhi * 4;
      long nn = n0 + wc * 64 + j * 16 + l15;
      if (nn < 64) {
        float bb = bq[nn];
#pragma unroll
        for (int r = 0; r < 4; ++r)
          Qb[(mm + r) * 64 + nn] = bf16b(acc[i][j][r] + bb);
      } else if (nn < 128) {
        float bb = bk[nn - 64];
#pragma unroll
        for (int r = 0; r < 4; ++r)
          Kb[(mm + r) * 64 + nn - 64] = bf16b(acc[i][j][r] + bb);
      } else {
        long c = nn - 128;
        float bb = bv[c];
        unsigned u01 = (unsigned)bf16b(acc[i][j][0] + bb) |
                       ((unsigned)bf16b(acc[i][j][1] + bb) << 16);
        unsigned u23 = (unsigned)bf16b(acc[i][j][2] + bb) |
                       ((unsigned)bf16b(acc[i][j][3] + bb) << 16);
        uint2 u; u.x = u01; u.y = u23;
        *(uint2*)&Vt[(mm >> 12) * 512 * 4096 + c * 4096 + (mm & 4095)] = u;
      }
    }
  }
}

// ---------------- softmax row stats (over j) via S recompute ----------------
// XCD remap: linear s -> b = s&7 pins all 128 blocks of batch b to one XCD
// (round-robin dispatch), keeping its K/Q panels (0.5MB each) L2-hot.
__global__ __launch_bounds__(256, 2) void stats_k(const u16* __restrict__ Qb,
                                                  const u16* __restrict__ Kb,
                                                  float* __restrict__ m_part,
                                                  float* __restrict__ l_part) {
  const int s = blockIdx.x + 32 * (blockIdx.y + 4 * blockIdx.z);
  const int b = s & 7;
  const int rest = s >> 3;          // 0..127
  const int jc = rest >> 5;         // 0..3
  const long i0 = (long)(rest & 31) * 128;
  const u16* Q = Qb + (long)b * 4096 * 64;
  const u16* Kp = Kb + (long)b * 4096 * 64;
  __shared__ __align__(16) u16 Qt[128 * 64];
  __shared__ __align__(16) u16 Kt[128 * 64];
  const int tid = threadIdx.x, lane = tid & 63, w = tid >> 6;
  const int l15 = lane & 15, lhi = lane >> 4;

#pragma unroll
  for (int it = 0; it < 4; ++it) {
    int q = it * 256 + tid;
    int row = q >> 3, c8 = q & 7;
    load16(Q + (i0 + row) * 64 + c8 * 8, &Qt[q * 8]);
  }

  float mrun[2][4], lrun[2][4];
#pragma unroll
  for (int i = 0; i < 2; ++i)
#pragma unroll
    for (int r = 0; r < 4; ++r) { mrun[i][r] = -1e30f; lrun[i][r] = 0.f; }

  for (int jt = 0; jt < 8; ++jt) {
    long j0 = (long)jc * 1024 + jt * 128;
#pragma unroll
    for (int it = 0; it < 4; ++it) {
      int q = it * 256 + tid;
      int row = q >> 3, c8 = q & 7;
      load16(Kp + (j0 + row) * 64 + c8 * 8, &Kt[q * 8]);
    }
    __syncthreads();
    f32x4 acc[2][8] = {};
#pragma unroll
    for (int kk = 0; kk < 64; kk += 32) {
      s16x8 af[2], bf[8];
#pragma unroll
      for (int i = 0; i < 2; ++i)
        af[i] = *(const s16x8*)&Qt[(w * 32 + i * 16 + l15) * 64 + kk + lhi * 8];
#pragma unroll
      for (int j = 0; j < 8; ++j)
        bf[j] = *(const s16x8*)&Kt[(j * 16 + l15) * 64 + kk + lhi * 8];
#pragma unroll
      for (int i = 0; i < 2; ++i)
#pragma unroll
        for (int j = 0; j < 8; ++j)
          acc[i][j] = __builtin_amdgcn_mfma_f32_16x16x32_bf16(af[i], bf[j],
                                                              acc[i][j], 0, 0, 0);
    }
#pragma unroll
    for (int i = 0; i < 2; ++i)
#pragma unroll
      for (int r = 0; r < 4; ++r) {
        float tm = acc[i][0][r];
#pragma unroll
        for (int j = 1; j < 8; ++j) tm = fmaxf(tm, acc[i][j][r]);
        float mo = mrun[i][r];
        float mn = fmaxf(mo, tm);
        float s2 = 0.f;
#pragma unroll
        for (int j = 0; j < 8; ++j) s2 += __expf(acc[i][j][r] - mn);
        lrun[i][r] = lrun[i][r] * __expf(mo - mn) + s2;
        mrun[i][r] = mn;
      }
    __syncthreads();
  }

#pragma unroll
  for (int i = 0; i < 2; ++i)
#pragma unroll
    for (int r = 0; r < 4; ++r) {
      float m = mrun[i][r], l = lrun[i][r];
#pragma unroll
      for (int d = 1; d < 16; d <<= 1) {
        float mo = __shfl_xor(m, d);
        float lo = __shfl_xor(l, d);
        float mn = fmaxf(m, mo);
        l = l * __expf(m - mn) + lo * __expf(mo - mn);
        m = mn;
      }
      if (l15 == 0) {
        long ig = i0 + w * 32 + i * 16 + lhi * 4 + r;
        long idx = ((long)(b * 4 + jc)) * 4096 + ig;
        m_part[idx] = m;
        l_part[idx] = l;
      }
    }
}

// merged stats: M2 = (m + ln l) * log2e, so P = exp2(s*log2e - M2)
__global__ __launch_bounds__(256) void merge_k(const float* __restrict__ m_part,
                                               const float* __restrict__ l_part,
                                               float* __restrict__ mfin) {
  int idx = blockIdx.x * 256 + threadIdx.x;  // 8*4096
  int b = idx >> 12, i = idx & 4095;
  float m = -1e30f, l = 0.f;
#pragma unroll
  for (int jc = 0; jc < 4; ++jc) {
    long o = ((long)(b * 4 + jc)) * 4096 + i;
    float mp = m_part[o], lp = l_part[o];
    float mn = fmaxf(m, mp);
    l = l * __expf(m - mn) + lp * __expf(mp - mn);
    m = mn;
  }
  mfin[idx] = fmaf(m, LOG2E, __log2f(l));
}

// ---------------- fused P·V v10 — no c-split, 1 barrier/iter (r10 best) ----
// 8-wave block (512 thr): out[b, j0:+128, 0:512]. Grid 32x8 = 256 = 1/CU.
// LDS 160KB: Vc[2] (V dbuf) + Pl[2] (P dbuf). Region(t), between barriers:
//   [bar: vmcnt(0) lgkm(0)]  // drains V(t) DMA (had full region to land)
//   qf/mv(t+1) -> reg; issue V(t+1) DMA -> Vc[~t]   (qf use waits counted)
//   GEMM2(t): Pl[t&1] x Vc[t&1] (setprio)  ||  GEMM1(t+1)+epi -> Pl[~t&1]
// Race matrix: every Vc/Pl write<->read pair separated by exactly 1 barrier.
__global__ __launch_bounds__(512, 2) void fusedPV(
    const u16* __restrict__ Qb, const u16* __restrict__ Kb,
    const u16* __restrict__ Vt, const float* __restrict__ mfin,
    const float* __restrict__ x, const float* __restrict__ gamma,
    float* __restrict__ out) {
  __shared__ __align__(16) u16 Vc[2][512 * 64];  // 128 KB
  __shared__ __align__(16) u16 Pl[2][128 * 64];  // 32 KB (Pl[0] = K staging)
  const int tid = threadIdx.x, lane = tid & 63, w = tid >> 6;  // w 0..7
  const int l15 = lane & 15, lhi = lane >> 4;
  const int wi = w & 1, wj = w >> 1;    // GEMM1: i-half(32) x j-quarter(32)
  const int wjj = w & 1, wcc = w >> 1;  // GEMM2: j-half(64) x c-quarter(128)
  // XCD remap: 256 blocks = 8 XCDs x 32; XCD k owns batch k (V 4MB = its L2)
  const int s = blockIdx.x + 32 * blockIdx.z;
  const int pi = (s & 7) * 32 + (s >> 3);
  const int b = pi >> 5;
  const long j0 = (long)(pi & 31) * 128;
  const u16* Qg = Qb + (long)b * 4096 * 64;
  const u16* Kg = Kb + (long)b * 4096 * 64;
  const u16* Vg = Vt + (long)b * 512 * 4096;
  const float* mg = mfin + (long)b * 4096;
  const float gma = gamma[0];

  // ---- prologue: stage K tile (128x128B) via Pl[0], hoist kf to regs ----
#pragma unroll
  for (int p = 0; p < 2; ++p) {
    int q = p * 512 + tid;
    int r = q >> 3, col = q & 7, cg = col ^ (r & 7);
    load16(Kg + (j0 + r) * 64 + cg * 8,
           (char*)&Pl[0][0] + r * 128 + col * 16);
  }
  asm volatile("s_waitcnt vmcnt(0) lgkmcnt(0)\n\ts_barrier" ::: "memory");
  s16x8 kf[2][2];  // loop-invariant K fragments (16 VGPR)
#pragma unroll
  for (int fj = 0; fj < 2; ++fj)
#pragma unroll
    for (int kx = 0; kx < 2; ++kx) {
      int r = wj * 32 + fj * 16 + l15;
      kf[fj][kx] = *(const s16x8*)((const char*)&Pl[0][0] + r * 128 +
                                   (((kx * 32 + lhi * 8) * 2) ^ ((r & 7) << 4)));
    }
  __syncthreads();  // kf reads done before Pl[0] reused for P

  f32x4 acc2[4][8] = {};
  s16x8 qf[2][2];
  f32x4 mv[2];

  // ---- t=0 preload: qf/mv first (so their use = counted), then V(0) DMA ----
#pragma unroll
  for (int fi = 0; fi < 2; ++fi) {
#pragma unroll
    for (int kx = 0; kx < 2; ++kx)
      qf[fi][kx] = *(const s16x8*)&Qg[(long)(wi * 32 + fi * 16 + l15) * 64 +
                                      kx * 32 + lhi * 8];
    mv[fi] = *(const f32x4*)&mg[wi * 32 + fi * 16 + lhi * 4];
  }
#pragma unroll
  for (int p = 0; p < 8; ++p) {
    int q = p * 512 + tid;
    int r = q >> 3, col = q & 7, cg = col ^ (r & 7);
    load16(Vg + (long)r * 4096 + cg * 8,
           (char*)&Vc[0][0] + r * 128 + col * 16);
  }
  // GEMM1(0) + epi -> Pl[0]
#pragma unroll
  for (int fi = 0; fi < 2; ++fi) {
    f32x4 a1[2] = {};
#pragma unroll
    for (int kx = 0; kx < 2; ++kx)
#pragma unroll
      for (int fj = 0; fj < 2; ++fj)
        a1[fj] = __builtin_amdgcn_mfma_f32_16x16x32_bf16(qf[fi][kx],
                                                         kf[fj][kx], a1[fj],
                                                         0, 0, 0);
    const int i0l = wi * 32 + fi * 16 + lhi * 4;
#pragma unroll
    for (int fj = 0; fj < 2; ++fj) {
      int j = wj * 32 + fj * 16 + l15;
      float p0 = __builtin_amdgcn_exp2f(fmaf(a1[fj][0], LOG2E, -mv[fi][0]));
      float p1 = __builtin_amdgcn_exp2f(fmaf(a1[fj][1], LOG2E, -mv[fi][1]));
      float p2 = __builtin_amdgcn_exp2f(fmaf(a1[fj][2], LOG2E, -mv[fi][2]));
      float p3 = __builtin_amdgcn_exp2f(fmaf(a1[fj][3], LOG2E, -mv[fi][3]));
      uint2 u;
      u.x = (unsigned)bf16b(p0) | ((unsigned)bf16b(p1) << 16);
      u.y = (unsigned)bf16b(p2) | ((unsigned)bf16b(p3) << 16);
      *(uint2*)((char*)&Pl[0][0] + j * 128 + ((i0l * 2) ^ ((j & 7) << 4))) = u;
    }
  }

  for (int t = 0; t < 64; ++t) {
    const char* plc = (const char*)&Pl[t & 1][0];
    char* pln = (char*)&Pl[(t + 1) & 1][0];
    const char* vcc = (const char*)&Vc[t & 1][0];
    // the ONE barrier: publish Pl[t&1]; drain V(t) DMA; free Vc[~t], Pl[~t]
    asm volatile("s_waitcnt vmcnt(0) lgkmcnt(0)\n\ts_barrier" ::: "memory");
    if (t < 63) {
      const long i2 = (long)(t + 1) * 64;
      // qf/mv(t+1) first (their use -> counted vmcnt, keeps DMA in flight)
#pragma unroll
      for (int fi = 0; fi < 2; ++fi) {
#pragma unroll
        for (int kx = 0; kx < 2; ++kx)
          qf[fi][kx] = *(const s16x8*)&Qg[(i2 + wi * 32 + fi * 16 + l15) * 64 +
                                          kx * 32 + lhi * 8];
        mv[fi] = *(const f32x4*)&mg[i2 + wi * 32 + fi * 16 + lhi * 4];
      }
      // V(t+1) DMA -> Vc[~t] (freed by the barrier above)
#pragma unroll
      for (int p = 0; p < 8; ++p) {
        int q = p * 512 + tid;
        int r = q >> 3, col = q & 7, cg = col ^ (r & 7);
        load16(Vg + (long)r * 4096 + i2 + cg * 8,
               (char*)&Vc[(t + 1) & 1][0] + r * 128 + col * 16);
      }
    }
    __builtin_amdgcn_sched_barrier(0);  // pin load issue before compute
    // GEMM2(t): acc2 += Pl[t&1](A; m=j) x Vc[t&1](B; n=c)
    __builtin_amdgcn_s_setprio(1);
#pragma unroll
    for (int kx = 0; kx < 2; ++kx) {
      s16x8 pa[4];
#pragma unroll
      for (int fm = 0; fm < 4; ++fm) {
        int r = wjj * 64 + fm * 16 + l15;
        pa[fm] = *(const s16x8*)(plc + r * 128 +
                                 (((kx * 32 + lhi * 8) * 2) ^ ((r & 7) << 4)));
      }
#pragma unroll
      for (int fn = 0; fn < 8; ++fn) {
        int r = wcc * 128 + fn * 16 + l15;
        s16x8 vb = *(const s16x8*)(vcc + r * 128 +
                                   (((kx * 32 + lhi * 8) * 2) ^ ((r & 7) << 4)));
#pragma unroll
        for (int fm = 0; fm < 4; ++fm)
          acc2[fm][fn] = __builtin_amdgcn_mfma_f32_16x16x32_bf16(
              pa[fm], vb, acc2[fm][fn], 0, 0, 0);
      }
    }
    __builtin_amdgcn_s_setprio(0);
    // GEMM1(t+1) + epi -> Pl[~t&1] (overlaps GEMM2 in the same region)
    if (t < 63) {
#pragma unroll
      for (int fi = 0; fi < 2; ++fi) {
        f32x4 a1[2] = {};
#pragma unroll
        for (int kx = 0; kx < 2; ++kx)
#pragma unroll
          for (int fj = 0; fj < 2; ++fj)
            a1[fj] = __builtin_amdgcn_mfma_f32_16x16x32_bf16(qf[fi][kx],
                                                             kf[fj][kx],
                                                             a1[fj], 0, 0, 0);
        const int i0l = wi * 32 + fi * 16 + lhi * 4;
#pragma unroll
        for (int fj = 0; fj < 2; ++fj) {
          int j = wj * 32 + fj * 16 + l15;
          float p0 = __builtin_amdgcn_exp2f(fmaf(a1[fj][0], LOG2E, -mv[fi][0]));
          float p1 = __builtin_amdgcn_exp2f(fmaf(a1[fj][1], LOG2E, -mv[fi][1]));
          float p2 = __builtin_amdgcn_exp2f(fmaf(a1[fj][2], LOG2E, -mv[fi][2]));
          float p3 = __builtin_amdgcn_exp2f(fmaf(a1[fj][3], LOG2E, -mv[fi][3]));
          uint2 u;
          u.x = (unsigned)bf16b(p0) | ((unsigned)bf16b(p1) << 16);
          u.y = (unsigned)bf16b(p2) | ((unsigned)bf16b(p3) << 16);
          *(uint2*)(pln + j * 128 + ((i0l * 2) ^ ((j & 7) << 4))) = u;
        }
      }
    }
  }

  // final epilogue: out = gamma*acc2 + x
#pragma unroll
  for (int fm = 0; fm < 4; ++fm) {
#pragma unroll
    for (int fn = 0; fn < 8; ++fn) {
      long j = j0 + wjj * 64 + fm * 16 + lhi * 4;
      long c = wcc * 128 + fn * 16 + l15;
#pragma unroll
      for (int r = 0; r < 4; ++r) {
        long o = ((long)b * 4096 + j + r) * 512 + c;
        out[o] = gma * acc2[fm][fn][r] + x[o];
      }
    }
  }
}

// ---------------- host ----------------

extern "C" void kernel_launch(void* const* d_in, const int* in_sizes, int n_in,
                              void* d_out, int out_size, void* d_ws,
                              size_t ws_size, hipStream_t stream) {
  const float* x = (const float*)d_in[0];
  const float* Wq = (const float*)d_in[1];
  const float* bq = (const float*)d_in[2];
  const float* Wk = (const float*)d_in[3];
  const float* bk = (const float*)d_in[4];
  const float* Wv = (const float*)d_in[5];
  const float* bv = (const float*)d_in[6];
  const float* gamma = (const float*)d_in[7];
  float* out = (float*)d_out;

  char* ws = (char*)d_ws;
  size_t off = 0;
  auto alloc = [&](size_t bytes) {
    char* p = ws + off;
    off += (bytes + 255) & ~(size_t)255;
    return p;
  };
  u16* xb = (u16*)alloc((size_t)32768 * 512 * 2);        // 32 MB
  u16* Wcat = (u16*)alloc((size_t)640 * 512 * 2);        // 640 KB
  u16* Qb = (u16*)alloc((size_t)8 * 4096 * 64 * 2);      // 4 MB
  u16* Kb = (u16*)alloc((size_t)8 * 4096 * 64 * 2);      // 4 MB
  u16* Vt = (u16*)alloc((size_t)8 * 512 * 4096 * 2);     // 32 MB
  float* m_part = (float*)alloc((size_t)8 * 4 * 4096 * 4);
  float* l_part = (float*)alloc((size_t)8 * 4 * 4096 * 4);
  float* mfin = (float*)alloc((size_t)8 * 4096 * 4);
  if (off > ws_size) {
    fprintf(stderr, "kernel_launch: ws too small: need %zu have %zu\n", off,
            ws_size);
    return;
  }

  // 1) dtype conversions (x + W in one launch)
  cvt_all_k<<<16384 + 1280, 256, 0, stream>>>(x, Wq, Wk, Wv, xb, Wcat);
  // 2) fused q/k/v projection GEMM (M=32768, N=640, K=512); writes Vt directly
  projGemm<<<dim3(256, 5, 1), 256, 0, stream>>>(xb, Wcat, Qb, Kb, Vt, bq, bk,
                                                bv);
  // 3) softmax row stats (recompute S)
  stats_k<<<dim3(32, 4, 8), 256, 0, stream>>>(Qb, Kb, m_part, l_part);
  merge_k<<<128, 256, 0, stream>>>(m_part, l_part, mfin);
  // 4) fused P recompute + P·V + residual epilogue (all 8 batches, full c)
  fusedPV<<<dim3(32, 1, 8), 512, 0, stream>>>(Qb, Kb, Vt, mfin, x, gamma,
                                              out);
}